// Round 14
// baseline (540.314 us; speedup 1.0000x reference)
//
#include <hip/hip_runtime.h>

// Problem constants
#define T     4
#define WQ    75
#define C     640
#define HW    100
#define WAY   5
#define SHOT  5
#define NT    5
#define NPAIR 15

// q tiles: [tq][tile(5)][oct(14)][row(128)][8] bf16; octet 12 half-zero, 13 zero
#define QOCT  14
#define QTS   (QOCT*128*8)        // 14336 shorts = 28 KB
// s tiles (tight k-pack): [tw][tile(5)][oct(64)][row(128)][8]; k = sh*100+n, 500 real + 12 zero
#define SOCT  64
#define STS   (SOCT*128*8)        // 65536 shorts = 128 KB

// ws layout (bytes)
#define WS_COVB_OFF  0            // 20*15*16384*2 = 9,830,400 (bf16, fragment order)
#define WS_QTB_OFF   9830400      // 300*5*14336*2 = 43,008,000
#define WS_QTBW_OFF  52838400     // 300*5*14336*2 = 43,008,000
#define WS_STB_OFF   95846400     // 20*5*65536*2  = 13,107,200

typedef __attribute__((ext_vector_type(8)))  short bfrag8;
typedef __attribute__((ext_vector_type(16))) float f32x16;
typedef __attribute__((ext_vector_type(2)))  float f32x2;

__device__ __forceinline__ unsigned short f2bf(float x) {
    unsigned int u = __float_as_uint(x);
    return (unsigned short)((u + 0x7fffu + ((u >> 16) & 1u)) >> 16);   // RNE
}
__device__ __forceinline__ float bflo(unsigned u) { return __uint_as_float(u << 16); }
__device__ __forceinline__ float bfhi(unsigned u) { return __uint_as_float(u & 0xffff0000u); }
__device__ __forceinline__ f32x2 bfpair(unsigned u) {
    f32x2 r;
    r.x = __uint_as_float(u << 16);
    r.y = __uint_as_float(u & 0xffff0000u);
    return r;
}

__device__ __forceinline__ void pair_ij(int p, int& ti, int& tj) {
    int base = 0;
    #pragma unroll
    for (int a = 0; a < NT; ++a) {
        int cnt = NT - a;
        if (p < base + cnt) { ti = a; tj = a + (p - base); return; }
        base += cnt;
    }
    ti = 0; tj = 0;
}

// ---------- merged spack + qpack (r4-proven); spack 8 rows/block, union LDS 16.2 KB ----------
#define LD2S 505
#define SROWS 8
#define NSPACK (20 * (C / SROWS))               // 20 tw * 80 rb = 1600
struct SpackSh { float ld2[SROWS * LD2S]; float mpart2[SROWS][32]; float mean2[SROWS]; }; // 16.2 KB
struct QpackSh { float ld[32 * 101]; float wl[HW]; float mpart[32][4]; float mean[32]; }; // 14 KB
union PackSh { SpackSh s; QpackSh q; };

__global__ __launch_bounds__(256, 8)
void pack_kernel(const float* __restrict__ qf, const float* __restrict__ sf,
                 const float* __restrict__ convw, const float* __restrict__ bias,
                 unsigned short* __restrict__ stb, unsigned short* __restrict__ qtb,
                 unsigned short* __restrict__ qtbw, float* __restrict__ out) {
    __shared__ PackSh sh;
    int bid = blockIdx.x, tid = threadIdx.x;

    if (bid < NSPACK) {
        // ---- spack: 8 rows/block, tight-k, stride 505 ----
        int rb = bid % 80, tw = bid / 80;
        int r0 = rb * SROWS;
        for (int sh_i = 0; sh_i < SHOT; ++sh_i) {
            const float* src = sf + ((size_t)(tw * SHOT + sh_i) * C + r0) * HW;
            if (tid < 200) {                     // 8 rows x 25 float4
                float4 v = ((const float4*)src)[tid];
                int f = tid * 4;
                int row = f / HW, n = f % HW;    // float4 never crosses a row
                float* d = &sh.s.ld2[row * LD2S + sh_i * HW + n];
                d[0] = v.x; d[1] = v.y; d[2] = v.z; d[3] = v.w;
            }
        }
        __syncthreads();
        {
            int row = tid & 7, part = tid >> 3;  // 32 parts x 16 els
            float ps = 0.f;
            #pragma unroll
            for (int i = 0; i < 16; ++i) {
                int k = part * 16 + i;
                if (k < 500) ps += sh.s.ld2[row * LD2S + k];
            }
            sh.s.mpart2[row][part] = ps;
        }
        __syncthreads();
        if (tid < SROWS) {
            float s2 = 0.f;
            #pragma unroll
            for (int p2 = 0; p2 < 32; ++p2) s2 += sh.s.mpart2[tid][p2];
            sh.s.mean2[tid] = s2 * (1.0f / (SHOT * HW));
        }
        __syncthreads();
        #pragma unroll
        for (int it = 0; it < 2; ++it) {
            int task = tid + it * 256;            // 512 tasks: oct(64) x row(8)
            int row = task & 7, oct = task >> 3;
            float m = sh.s.mean2[row];
            unsigned short ob[8] __attribute__((aligned(16)));
            #pragma unroll
            for (int j = 0; j < 8; ++j) {
                int k = oct * 8 + j;
                ob[j] = (k < 500) ? f2bf(sh.s.ld2[row * LD2S + k] - m) : (unsigned short)0;
            }
            int crow = r0 + row;
            int tile = crow >> 7, trow = crow & 127;
            size_t dst = ((((size_t)tw * NT + tile) * SOCT + oct) * 128 + trow) * 8;
            *(uint4*)(stb + dst) = *(uint4*)ob;
        }
    } else {
        // ---- qpack: 32 rows/block ----
        int idx0 = bid - NSPACK;
        int cb = idx0 % 20, tq = idx0 / 20;
        if (idx0 == 0) {                          // folded out-init (completes before score)
            float b = bias[0];
            for (int i = tid; i < T * WQ * WAY; i += 256) out[i] = b;
        }
        if (tid < HW) sh.q.wl[tid] = convw[tid];
        const float* src = qf + ((size_t)tq * C + cb * 32) * HW;
        #pragma unroll
        for (int it = 0; it < 4; ++it) {
            int idx = tid + it * 256;
            if (idx < 800) {                      // 32 rows x 25 float4
                float4 v = ((const float4*)src)[idx];
                int f = idx * 4;
                int row = f / HW, n = f % HW;
                float* d = &sh.q.ld[row * 101 + n];
                d[0] = v.x; d[1] = v.y; d[2] = v.z; d[3] = v.w;
            }
        }
        __syncthreads();
        if (tid < 128) {
            int row = tid & 31, part = tid >> 5;
            float ps = 0.f;
            #pragma unroll
            for (int i = 0; i < 25; ++i) ps += sh.q.ld[row * 101 + part * 25 + i];
            sh.q.mpart[row][part] = ps;
        }
        __syncthreads();
        if (tid < 32) sh.q.mean[tid] = (sh.q.mpart[tid][0] + sh.q.mpart[tid][1]
                                      + sh.q.mpart[tid][2] + sh.q.mpart[tid][3]) * (1.0f / HW);
        __syncthreads();
        int crow0 = cb * 32;
        int tile = crow0 >> 7, trowbase = crow0 & 127;
        #pragma unroll
        for (int it = 0; it < 2; ++it) {
            int task = tid + it * 256;            // 448 tasks: row(32) x oct(14)
            if (task < 32 * QOCT) {
                int row = task & 31, oct = task >> 5;
                float m = sh.q.mean[row];
                unsigned short ob[8] __attribute__((aligned(16)));
                unsigned short ow[8] __attribute__((aligned(16)));
                #pragma unroll
                for (int j = 0; j < 8; ++j) {
                    int n = oct * 8 + j;
                    float v = (n < HW) ? (sh.q.ld[row * 101 + n] - m) : 0.f;
                    float w = (n < HW) ? sh.q.wl[n] : 0.f;
                    ob[j] = f2bf(v); ow[j] = f2bf(v * w);
                }
                size_t dst = ((((size_t)tq * NT + tile) * QOCT + oct) * 128 + trowbase + row) * 8;
                *(uint4*)(qtb + dst)  = *(uint4*)ob;
                *(uint4*)(qtbw + dst) = *(uint4*)ow;
            }
        }
    }
}

// ---------- cov: direct global->VGPR fragment loads, tight k (32 s-iters). 300 blocks ----------
__global__ __launch_bounds__(256, 3)
void cov_kernel(const unsigned short* __restrict__ stb, unsigned short* __restrict__ covb) {
    int bid = blockIdx.x, tid = threadIdx.x;
    int p = bid % NPAIR, tw = bid / NPAIR;
    int ti, tj; pair_ij(p, ti, tj);
    int lane = tid & 63, wave = tid >> 6;
    int qm = wave & 1, qn = wave >> 1, lh = lane >> 5, ls = lane & 31;
    int rA = qm * 64 + ls, rB = qn * 64 + ls;
    const unsigned short* Ab = stb + ((size_t)tw * NT + ti) * STS;
    const unsigned short* Bb = stb + ((size_t)tw * NT + tj) * STS;

    f32x16 acc[4];
    #pragma unroll
    for (int b = 0; b < 4; ++b)
        #pragma unroll
        for (int e = 0; e < 16; ++e) acc[b][e] = 0.f;

    #pragma unroll 4
    for (int s = 0; s < 32; ++s) {
        int oc = s * 2 + lh;
        const unsigned short* ap = Ab + (size_t)oc * 1024;
        const unsigned short* bp = Bb + (size_t)oc * 1024;
        bfrag8 a0 = *(const bfrag8*)&ap[rA * 8];
        bfrag8 a1 = *(const bfrag8*)&ap[(rA + 32) * 8];
        bfrag8 b0 = *(const bfrag8*)&bp[rB * 8];
        bfrag8 b1 = *(const bfrag8*)&bp[(rB + 32) * 8];
        acc[0] = __builtin_amdgcn_mfma_f32_32x32x16_bf16(a0, b0, acc[0], 0, 0, 0);
        acc[1] = __builtin_amdgcn_mfma_f32_32x32x16_bf16(a0, b1, acc[1], 0, 0, 0);
        acc[2] = __builtin_amdgcn_mfma_f32_32x32x16_bf16(a1, b0, acc[2], 0, 0, 0);
        acc[3] = __builtin_amdgcn_mfma_f32_32x32x16_bf16(a1, b1, acc[3], 0, 0, 0);
    }

    const float inv = 1.0f / (HW - 1);
    unsigned short* cbp = covb + ((size_t)tw * NPAIR + p) * 16384;
    #pragma unroll
    for (int b = 0; b < 4; ++b) {
        unsigned ow[8];
        #pragma unroll
        for (int wd = 0; wd < 8; ++wd)
            ow[wd] = (unsigned)f2bf(acc[b][2 * wd] * inv)
                   | ((unsigned)f2bf(acc[b][2 * wd + 1] * inv) << 16);
        size_t off = (size_t)((wave * 4 + b) * 64 + lane) * 16;
        *(uint4*)(cbp + off)     = *(uint4*)&ow[0];
        *(uint4*)(cbp + off + 8) = *(uint4*)&ow[4];
    }
}

// ---------- score v14 = r13's exact body; launch_bounds (256,3) -> (256,6) ----------
// Occupancy ledger: achieved waves/EU tracks the 2nd launch_bounds arg in all four
// measured configs (2->1.9, 3->2.7, 2->1.6 at 64thr), even with VGPR=60 and LDS=512B
// permitting 8/EU. Score is latency-bound (VALU 38%, MFMA 12.5%, HBM 13%) -> raise
// the target to 6 (VGPR budget ~85 >> current 60; 8's hard 64-cap is riskier).
__global__ __launch_bounds__(256, 6)
void score_kernel(const unsigned short* __restrict__ qtb, const unsigned short* __restrict__ qtbw,
                  const unsigned short* __restrict__ covb, float* __restrict__ out) {
    __shared__ float red[4][WAY];
    int orig = blockIdx.x;
    int xcd = orig & 7, slot = orig >> 3;
    int wgid = (xcd < 4) ? (xcd * 563 + slot) : (2252 + (xcd - 4) * 562 + slot);
    int p = wgid % NPAIR;
    int tq = wgid / NPAIR;                       // 0..299
    int t = tq / WQ, q = tq % WQ;
    int ti, tj; pair_ij(p, ti, tj);
    int tid = threadIdx.x, lane = tid & 63, wave = tid >> 6;
    int qm = wave & 1, qn = wave >> 1, lh = lane >> 5, ls = lane & 31;
    int rA = qm * 64 + ls, rB = qn * 64 + ls;
    float mult = (ti == tj) ? 1.0f : 2.0f;

    const unsigned short* Ab = qtbw + ((size_t)(t * WQ + q) * NT + ti) * QTS;
    const unsigned short* Bb = qtb  + ((size_t)(t * WQ + q) * NT + tj) * QTS;

    f32x16 acc[4];
    #pragma unroll
    for (int b = 0; b < 4; ++b)
        #pragma unroll
        for (int e = 0; e < 16; ++e) acc[b][e] = 0.f;

    #pragma unroll
    for (int s = 0; s < 7; ++s) {
        int oc = s * 2 + lh;
        const unsigned short* ap = Ab + (size_t)oc * 1024;
        const unsigned short* bp = Bb + (size_t)oc * 1024;
        bfrag8 a0 = *(const bfrag8*)&ap[rA * 8];
        bfrag8 a1 = *(const bfrag8*)&ap[(rA + 32) * 8];
        bfrag8 b0 = *(const bfrag8*)&bp[rB * 8];
        bfrag8 b1 = *(const bfrag8*)&bp[(rB + 32) * 8];
        acc[0] = __builtin_amdgcn_mfma_f32_32x32x16_bf16(a0, b0, acc[0], 0, 0, 0);
        acc[1] = __builtin_amdgcn_mfma_f32_32x32x16_bf16(a0, b1, acc[1], 0, 0, 0);
        acc[2] = __builtin_amdgcn_mfma_f32_32x32x16_bf16(a1, b0, acc[2], 0, 0, 0);
        acc[3] = __builtin_amdgcn_mfma_f32_32x32x16_bf16(a1, b1, acc[3], 0, 0, 0);
    }

    // per-way Frobenius dot: 8-wide uint4 burst, packed-f32 FMA chains, per-way reduce.
    // unroll 1 keeps live cov footprint at 8 uint4 (no scratch-spill risk).
    const unsigned short* cb0 = covb + ((size_t)(t * WAY) * NPAIR + p) * 16384
                              + (size_t)(wave * 4096 + lane * 16);
    #pragma unroll 1
    for (int w = 0; w < WAY; ++w) {
        const unsigned short* cbw = cb0 + (size_t)w * (NPAIR * 16384);
        uint4 cu[8];
        #pragma unroll
        for (int b = 0; b < 4; ++b) {
            cu[2 * b]     = *(const uint4*)(cbw + b * 1024);
            cu[2 * b + 1] = *(const uint4*)(cbw + b * 1024 + 8);
        }
        f32x2 s0 = {0.f, 0.f}, s1 = {0.f, 0.f}, s2 = {0.f, 0.f}, s3 = {0.f, 0.f};
        #pragma unroll
        for (int b = 0; b < 4; ++b) {
            #pragma unroll
            for (int h = 0; h < 2; ++h) {
                uint4 u = cu[2 * b + h];
                int e = h * 8;
                f32x2 a0 = {acc[b][e + 0], acc[b][e + 1]};
                f32x2 a1 = {acc[b][e + 2], acc[b][e + 3]};
                f32x2 a2 = {acc[b][e + 4], acc[b][e + 5]};
                f32x2 a3 = {acc[b][e + 6], acc[b][e + 7]};
                s0 = __builtin_elementwise_fma(bfpair(u.x), a0, s0);
                s1 = __builtin_elementwise_fma(bfpair(u.y), a1, s1);
                s2 = __builtin_elementwise_fma(bfpair(u.z), a2, s2);
                s3 = __builtin_elementwise_fma(bfpair(u.w), a3, s3);
            }
        }
        float v = (((s0.x + s0.y) + (s1.x + s1.y)) + ((s2.x + s2.y) + (s3.x + s3.y))) * mult;
        #pragma unroll
        for (int off2 = 32; off2 > 0; off2 >>= 1) v += __shfl_down(v, off2);
        if (lane == 0) red[wave][w] = v;
    }
    __syncthreads();
    if (tid < WAY) {
        float tot = red[0][tid] + red[1][tid] + red[2][tid] + red[3][tid];
        atomicAdd(&out[(size_t)(t * WQ + q) * WAY + tid], tot);
    }
}

extern "C" void kernel_launch(void* const* d_in, const int* in_sizes, int n_in,
                              void* d_out, int out_size, void* d_ws, size_t ws_size,
                              hipStream_t stream) {
    const float* qf = (const float*)d_in[0];   // (4,75,640,10,10)
    const float* sf = (const float*)d_in[1];   // (4,25,640,10,10)
    const float* cw = (const float*)d_in[2];   // (1,1,100)
    const float* cb = (const float*)d_in[3];   // (1,)
    float* out = (float*)d_out;                // (4,75,5)

    unsigned short* covb = (unsigned short*)((char*)d_ws + WS_COVB_OFF);
    unsigned short* qtb  = (unsigned short*)((char*)d_ws + WS_QTB_OFF);
    unsigned short* qtbw = (unsigned short*)((char*)d_ws + WS_QTBW_OFF);
    unsigned short* stb  = (unsigned short*)((char*)d_ws + WS_STB_OFF);

    pack_kernel<<<NSPACK + 6000, 256, 0, stream>>>(qf, sf, cw, cb, stb, qtb, qtbw, out);
    cov_kernel<<<300, 256, 0, stream>>>(stb, covb);
    score_kernel<<<4500, 256, 0, stream>>>(qtb, qtbw, covb, out);
}

// Round 15
// 206.174 us; speedup vs baseline: 2.6207x; 2.6207x over previous
//
#include <hip/hip_runtime.h>

// Problem constants
#define T     4
#define WQ    75
#define C     640
#define HW    100
#define WAY   5
#define SHOT  5
#define NT    5
#define NPAIR 15

// q tiles: [tq][tile(5)][oct(14)][row(128)][8] bf16; octet 12 half-zero, 13 zero
#define QOCT  14
#define QTS   (QOCT*128*8)        // 14336 shorts = 28 KB
// s tiles (tight k-pack): [tw][tile(5)][oct(64)][row(128)][8]; k = sh*100+n, 500 real + 12 zero
#define SOCT  64
#define STS   (SOCT*128*8)        // 65536 shorts = 128 KB

// ws layout (bytes)
#define WS_COVB_OFF  0            // 20*15*16384*2 = 9,830,400 (bf16, fragment order)
#define WS_QTB_OFF   9830400      // 300*5*14336*2 = 43,008,000
#define WS_QTBW_OFF  52838400     // 300*5*14336*2 = 43,008,000
#define WS_STB_OFF   95846400     // 20*5*65536*2  = 13,107,200

typedef __attribute__((ext_vector_type(8)))  short bfrag8;
typedef __attribute__((ext_vector_type(16))) float f32x16;
typedef __attribute__((ext_vector_type(2)))  float f32x2;

__device__ __forceinline__ unsigned short f2bf(float x) {
    unsigned int u = __float_as_uint(x);
    return (unsigned short)((u + 0x7fffu + ((u >> 16) & 1u)) >> 16);   // RNE
}
__device__ __forceinline__ float bflo(unsigned u) { return __uint_as_float(u << 16); }
__device__ __forceinline__ float bfhi(unsigned u) { return __uint_as_float(u & 0xffff0000u); }
__device__ __forceinline__ f32x2 bfpair(unsigned u) {
    f32x2 r;
    r.x = __uint_as_float(u << 16);
    r.y = __uint_as_float(u & 0xffff0000u);
    return r;
}

__device__ __forceinline__ void pair_ij(int p, int& ti, int& tj) {
    int base = 0;
    #pragma unroll
    for (int a = 0; a < NT; ++a) {
        int cnt = NT - a;
        if (p < base + cnt) { ti = a; tj = a + (p - base); return; }
        base += cnt;
    }
    ti = 0; tj = 0;
}

// ---------- merged spack + qpack (r4-proven); spack 8 rows/block, union LDS 16.2 KB ----------
#define LD2S 505
#define SROWS 8
#define NSPACK (20 * (C / SROWS))               // 20 tw * 80 rb = 1600
struct SpackSh { float ld2[SROWS * LD2S]; float mpart2[SROWS][32]; float mean2[SROWS]; }; // 16.2 KB
struct QpackSh { float ld[32 * 101]; float wl[HW]; float mpart[32][4]; float mean[32]; }; // 14 KB
union PackSh { SpackSh s; QpackSh q; };

__global__ __launch_bounds__(256, 8)
void pack_kernel(const float* __restrict__ qf, const float* __restrict__ sf,
                 const float* __restrict__ convw, const float* __restrict__ bias,
                 unsigned short* __restrict__ stb, unsigned short* __restrict__ qtb,
                 unsigned short* __restrict__ qtbw, float* __restrict__ out) {
    __shared__ PackSh sh;
    int bid = blockIdx.x, tid = threadIdx.x;

    if (bid < NSPACK) {
        // ---- spack: 8 rows/block, tight-k, stride 505 ----
        int rb = bid % 80, tw = bid / 80;
        int r0 = rb * SROWS;
        for (int sh_i = 0; sh_i < SHOT; ++sh_i) {
            const float* src = sf + ((size_t)(tw * SHOT + sh_i) * C + r0) * HW;
            if (tid < 200) {                     // 8 rows x 25 float4
                float4 v = ((const float4*)src)[tid];
                int f = tid * 4;
                int row = f / HW, n = f % HW;    // float4 never crosses a row
                float* d = &sh.s.ld2[row * LD2S + sh_i * HW + n];
                d[0] = v.x; d[1] = v.y; d[2] = v.z; d[3] = v.w;
            }
        }
        __syncthreads();
        {
            int row = tid & 7, part = tid >> 3;  // 32 parts x 16 els
            float ps = 0.f;
            #pragma unroll
            for (int i = 0; i < 16; ++i) {
                int k = part * 16 + i;
                if (k < 500) ps += sh.s.ld2[row * LD2S + k];
            }
            sh.s.mpart2[row][part] = ps;
        }
        __syncthreads();
        if (tid < SROWS) {
            float s2 = 0.f;
            #pragma unroll
            for (int p2 = 0; p2 < 32; ++p2) s2 += sh.s.mpart2[tid][p2];
            sh.s.mean2[tid] = s2 * (1.0f / (SHOT * HW));
        }
        __syncthreads();
        #pragma unroll
        for (int it = 0; it < 2; ++it) {
            int task = tid + it * 256;            // 512 tasks: oct(64) x row(8)
            int row = task & 7, oct = task >> 3;
            float m = sh.s.mean2[row];
            unsigned short ob[8] __attribute__((aligned(16)));
            #pragma unroll
            for (int j = 0; j < 8; ++j) {
                int k = oct * 8 + j;
                ob[j] = (k < 500) ? f2bf(sh.s.ld2[row * LD2S + k] - m) : (unsigned short)0;
            }
            int crow = r0 + row;
            int tile = crow >> 7, trow = crow & 127;
            size_t dst = ((((size_t)tw * NT + tile) * SOCT + oct) * 128 + trow) * 8;
            *(uint4*)(stb + dst) = *(uint4*)ob;
        }
    } else {
        // ---- qpack: 32 rows/block ----
        int idx0 = bid - NSPACK;
        int cb = idx0 % 20, tq = idx0 / 20;
        if (idx0 == 0) {                          // folded out-init (completes before score)
            float b = bias[0];
            for (int i = tid; i < T * WQ * WAY; i += 256) out[i] = b;
        }
        if (tid < HW) sh.q.wl[tid] = convw[tid];
        const float* src = qf + ((size_t)tq * C + cb * 32) * HW;
        #pragma unroll
        for (int it = 0; it < 4; ++it) {
            int idx = tid + it * 256;
            if (idx < 800) {                      // 32 rows x 25 float4
                float4 v = ((const float4*)src)[idx];
                int f = idx * 4;
                int row = f / HW, n = f % HW;
                float* d = &sh.q.ld[row * 101 + n];
                d[0] = v.x; d[1] = v.y; d[2] = v.z; d[3] = v.w;
            }
        }
        __syncthreads();
        if (tid < 128) {
            int row = tid & 31, part = tid >> 5;
            float ps = 0.f;
            #pragma unroll
            for (int i = 0; i < 25; ++i) ps += sh.q.ld[row * 101 + part * 25 + i];
            sh.q.mpart[row][part] = ps;
        }
        __syncthreads();
        if (tid < 32) sh.q.mean[tid] = (sh.q.mpart[tid][0] + sh.q.mpart[tid][1]
                                      + sh.q.mpart[tid][2] + sh.q.mpart[tid][3]) * (1.0f / HW);
        __syncthreads();
        int crow0 = cb * 32;
        int tile = crow0 >> 7, trowbase = crow0 & 127;
        #pragma unroll
        for (int it = 0; it < 2; ++it) {
            int task = tid + it * 256;            // 448 tasks: row(32) x oct(14)
            if (task < 32 * QOCT) {
                int row = task & 31, oct = task >> 5;
                float m = sh.q.mean[row];
                unsigned short ob[8] __attribute__((aligned(16)));
                unsigned short ow[8] __attribute__((aligned(16)));
                #pragma unroll
                for (int j = 0; j < 8; ++j) {
                    int n = oct * 8 + j;
                    float v = (n < HW) ? (sh.q.ld[row * 101 + n] - m) : 0.f;
                    float w = (n < HW) ? sh.q.wl[n] : 0.f;
                    ob[j] = f2bf(v); ow[j] = f2bf(v * w);
                }
                size_t dst = ((((size_t)tq * NT + tile) * QOCT + oct) * 128 + trowbase + row) * 8;
                *(uint4*)(qtb + dst)  = *(uint4*)ob;
                *(uint4*)(qtbw + dst) = *(uint4*)ow;
            }
        }
    }
}

// ---------- cov: direct global->VGPR fragment loads, tight k (32 s-iters). 300 blocks ----------
__global__ __launch_bounds__(256, 3)
void cov_kernel(const unsigned short* __restrict__ stb, unsigned short* __restrict__ covb) {
    int bid = blockIdx.x, tid = threadIdx.x;
    int p = bid % NPAIR, tw = bid / NPAIR;
    int ti, tj; pair_ij(p, ti, tj);
    int lane = tid & 63, wave = tid >> 6;
    int qm = wave & 1, qn = wave >> 1, lh = lane >> 5, ls = lane & 31;
    int rA = qm * 64 + ls, rB = qn * 64 + ls;
    const unsigned short* Ab = stb + ((size_t)tw * NT + ti) * STS;
    const unsigned short* Bb = stb + ((size_t)tw * NT + tj) * STS;

    f32x16 acc[4];
    #pragma unroll
    for (int b = 0; b < 4; ++b)
        #pragma unroll
        for (int e = 0; e < 16; ++e) acc[b][e] = 0.f;

    #pragma unroll 4
    for (int s = 0; s < 32; ++s) {
        int oc = s * 2 + lh;
        const unsigned short* ap = Ab + (size_t)oc * 1024;
        const unsigned short* bp = Bb + (size_t)oc * 1024;
        bfrag8 a0 = *(const bfrag8*)&ap[rA * 8];
        bfrag8 a1 = *(const bfrag8*)&ap[(rA + 32) * 8];
        bfrag8 b0 = *(const bfrag8*)&bp[rB * 8];
        bfrag8 b1 = *(const bfrag8*)&bp[(rB + 32) * 8];
        acc[0] = __builtin_amdgcn_mfma_f32_32x32x16_bf16(a0, b0, acc[0], 0, 0, 0);
        acc[1] = __builtin_amdgcn_mfma_f32_32x32x16_bf16(a0, b1, acc[1], 0, 0, 0);
        acc[2] = __builtin_amdgcn_mfma_f32_32x32x16_bf16(a1, b0, acc[2], 0, 0, 0);
        acc[3] = __builtin_amdgcn_mfma_f32_32x32x16_bf16(a1, b1, acc[3], 0, 0, 0);
    }

    const float inv = 1.0f / (HW - 1);
    unsigned short* cbp = covb + ((size_t)tw * NPAIR + p) * 16384;
    #pragma unroll
    for (int b = 0; b < 4; ++b) {
        unsigned ow[8];
        #pragma unroll
        for (int wd = 0; wd < 8; ++wd)
            ow[wd] = (unsigned)f2bf(acc[b][2 * wd] * inv)
                   | ((unsigned)f2bf(acc[b][2 * wd + 1] * inv) << 16);
        size_t off = (size_t)((wave * 4 + b) * 64 + lane) * 16;
        *(uint4*)(cbp + off)     = *(uint4*)&ow[0];
        *(uint4*)(cbp + off + 8) = *(uint4*)&ow[4];
    }
}

// ---------- score v15 = r13's exact body; launch_bounds (256,3) -> (256,4) ----------
// r14 ledger: (256,6) made the allocator snap to VGPR=40 < the 64-VGPR accumulator
// -> 859 MB scratch, 402us. The arg is not a free dial. (256,4) keeps a 128-VGPR
// budget (2x the 60-VGPR need) — the mildest possible occupancy bump over the
// proven (256,3). Tripwire: WRITE_SIZE >= 1 MB means spill -> r13 is the endpoint.
__global__ __launch_bounds__(256, 4)
void score_kernel(const unsigned short* __restrict__ qtb, const unsigned short* __restrict__ qtbw,
                  const unsigned short* __restrict__ covb, float* __restrict__ out) {
    __shared__ float red[4][WAY];
    int orig = blockIdx.x;
    int xcd = orig & 7, slot = orig >> 3;
    int wgid = (xcd < 4) ? (xcd * 563 + slot) : (2252 + (xcd - 4) * 562 + slot);
    int p = wgid % NPAIR;
    int tq = wgid / NPAIR;                       // 0..299
    int t = tq / WQ, q = tq % WQ;
    int ti, tj; pair_ij(p, ti, tj);
    int tid = threadIdx.x, lane = tid & 63, wave = tid >> 6;
    int qm = wave & 1, qn = wave >> 1, lh = lane >> 5, ls = lane & 31;
    int rA = qm * 64 + ls, rB = qn * 64 + ls;
    float mult = (ti == tj) ? 1.0f : 2.0f;

    const unsigned short* Ab = qtbw + ((size_t)(t * WQ + q) * NT + ti) * QTS;
    const unsigned short* Bb = qtb  + ((size_t)(t * WQ + q) * NT + tj) * QTS;

    f32x16 acc[4];
    #pragma unroll
    for (int b = 0; b < 4; ++b)
        #pragma unroll
        for (int e = 0; e < 16; ++e) acc[b][e] = 0.f;

    #pragma unroll
    for (int s = 0; s < 7; ++s) {
        int oc = s * 2 + lh;
        const unsigned short* ap = Ab + (size_t)oc * 1024;
        const unsigned short* bp = Bb + (size_t)oc * 1024;
        bfrag8 a0 = *(const bfrag8*)&ap[rA * 8];
        bfrag8 a1 = *(const bfrag8*)&ap[(rA + 32) * 8];
        bfrag8 b0 = *(const bfrag8*)&bp[rB * 8];
        bfrag8 b1 = *(const bfrag8*)&bp[(rB + 32) * 8];
        acc[0] = __builtin_amdgcn_mfma_f32_32x32x16_bf16(a0, b0, acc[0], 0, 0, 0);
        acc[1] = __builtin_amdgcn_mfma_f32_32x32x16_bf16(a0, b1, acc[1], 0, 0, 0);
        acc[2] = __builtin_amdgcn_mfma_f32_32x32x16_bf16(a1, b0, acc[2], 0, 0, 0);
        acc[3] = __builtin_amdgcn_mfma_f32_32x32x16_bf16(a1, b1, acc[3], 0, 0, 0);
    }

    // per-way Frobenius dot: 8-wide uint4 burst, packed-f32 FMA chains, per-way reduce.
    // unroll 1 keeps live cov footprint at 8 uint4 (no scratch-spill risk).
    const unsigned short* cb0 = covb + ((size_t)(t * WAY) * NPAIR + p) * 16384
                              + (size_t)(wave * 4096 + lane * 16);
    #pragma unroll 1
    for (int w = 0; w < WAY; ++w) {
        const unsigned short* cbw = cb0 + (size_t)w * (NPAIR * 16384);
        uint4 cu[8];
        #pragma unroll
        for (int b = 0; b < 4; ++b) {
            cu[2 * b]     = *(const uint4*)(cbw + b * 1024);
            cu[2 * b + 1] = *(const uint4*)(cbw + b * 1024 + 8);
        }
        f32x2 s0 = {0.f, 0.f}, s1 = {0.f, 0.f}, s2 = {0.f, 0.f}, s3 = {0.f, 0.f};
        #pragma unroll
        for (int b = 0; b < 4; ++b) {
            #pragma unroll
            for (int h = 0; h < 2; ++h) {
                uint4 u = cu[2 * b + h];
                int e = h * 8;
                f32x2 a0 = {acc[b][e + 0], acc[b][e + 1]};
                f32x2 a1 = {acc[b][e + 2], acc[b][e + 3]};
                f32x2 a2 = {acc[b][e + 4], acc[b][e + 5]};
                f32x2 a3 = {acc[b][e + 6], acc[b][e + 7]};
                s0 = __builtin_elementwise_fma(bfpair(u.x), a0, s0);
                s1 = __builtin_elementwise_fma(bfpair(u.y), a1, s1);
                s2 = __builtin_elementwise_fma(bfpair(u.z), a2, s2);
                s3 = __builtin_elementwise_fma(bfpair(u.w), a3, s3);
            }
        }
        float v = (((s0.x + s0.y) + (s1.x + s1.y)) + ((s2.x + s2.y) + (s3.x + s3.y))) * mult;
        #pragma unroll
        for (int off2 = 32; off2 > 0; off2 >>= 1) v += __shfl_down(v, off2);
        if (lane == 0) red[wave][w] = v;
    }
    __syncthreads();
    if (tid < WAY) {
        float tot = red[0][tid] + red[1][tid] + red[2][tid] + red[3][tid];
        atomicAdd(&out[(size_t)(t * WQ + q) * WAY + tid], tot);
    }
}

extern "C" void kernel_launch(void* const* d_in, const int* in_sizes, int n_in,
                              void* d_out, int out_size, void* d_ws, size_t ws_size,
                              hipStream_t stream) {
    const float* qf = (const float*)d_in[0];   // (4,75,640,10,10)
    const float* sf = (const float*)d_in[1];   // (4,25,640,10,10)
    const float* cw = (const float*)d_in[2];   // (1,1,100)
    const float* cb = (const float*)d_in[3];   // (1,)
    float* out = (float*)d_out;                // (4,75,5)

    unsigned short* covb = (unsigned short*)((char*)d_ws + WS_COVB_OFF);
    unsigned short* qtb  = (unsigned short*)((char*)d_ws + WS_QTB_OFF);
    unsigned short* qtbw = (unsigned short*)((char*)d_ws + WS_QTBW_OFF);
    unsigned short* stb  = (unsigned short*)((char*)d_ws + WS_STB_OFF);

    pack_kernel<<<NSPACK + 6000, 256, 0, stream>>>(qf, sf, cw, cb, stb, qtb, qtbw, out);
    cov_kernel<<<300, 256, 0, stream>>>(stb, covb);
    score_kernel<<<4500, 256, 0, stream>>>(qtb, qtbw, covb, out);
}